// Round 5
// baseline (35249.860 us; speedup 1.0000x reference)
//
#include <hip/hip_runtime.h>
#include <stdint.h>

typedef unsigned long long u64;

#define Bq 64
#define Tq 256
#define Hq 512
#define Eq 512
#define Vq 32000
#define NBLK 256

__device__ __forceinline__ float sigmoid_f(float x) { return 1.0f / (1.0f + expf(-x)); }

__device__ __forceinline__ unsigned f2sortable(float f) {
    unsigned u = __float_as_uint(f);
    return (u & 0x80000000u) ? ~u : (u | 0x80000000u);
}

// async global->LDS, 16B per lane; LDS dest is wave-uniform base + lane*16
__device__ __forceinline__ void gl_lds16(const float* g, float* l) {
    __builtin_amdgcn_global_load_lds(
        (const __attribute__((address_space(1))) void*)g,
        (__attribute__((address_space(3))) void*)l, 16, 0, 0);
}

#define DOT4(acc, a, wv) \
    acc = fmaf((a).w, (wv).w, fmaf((a).z, (wv).z, fmaf((a).y, (wv).y, fmaf((a).x, (wv).x, (acc)))))

// ---------------------------------------------------------------------------
// Manual device-wide barrier: generation counter, AGENT-scope atomics.
// Safe because all NBLK blocks are co-resident by construction (see launch).
// ---------------------------------------------------------------------------
__device__ __forceinline__ void gbar(unsigned* cnt, unsigned* gen) {
    __syncthreads();
    if (threadIdx.x == 0) {
        unsigned g = __hip_atomic_load(gen, __ATOMIC_RELAXED, __HIP_MEMORY_SCOPE_AGENT);
        __threadfence();
        unsigned a = __hip_atomic_fetch_add(cnt, 1u, __ATOMIC_ACQ_REL, __HIP_MEMORY_SCOPE_AGENT);
        if (a == NBLK - 1u) {
            __hip_atomic_store(cnt, 0u, __ATOMIC_RELAXED, __HIP_MEMORY_SCOPE_AGENT);
            __hip_atomic_store(gen, g + 1u, __ATOMIC_RELEASE, __HIP_MEMORY_SCOPE_AGENT);
        } else {
            while (__hip_atomic_load(gen, __ATOMIC_ACQUIRE, __HIP_MEMORY_SCOPE_AGENT) == g)
                __builtin_amdgcn_s_sleep(2);
        }
        __threadfence();
    }
    __syncthreads();
}

// ---------------------------------------------------------------------------
// LSTM phase: 512-thread block handles TWO hidden units (waves 0-3: unit h,
// waves 4-7: unit h+256). Per-unit math byte-identical to the round-3 kernel.
// myl points to this unit's 5120-float LDS slice (4096 wlds + 1024 red).
// ---------------------------------------------------------------------------
__device__ __forceinline__ void lstm_phase(
    float* myl, int h, int wsub, int tsub,
    const float* __restrict__ emb, const int* __restrict__ xcol,
    const u64* __restrict__ amax_in,
    const float* __restrict__ inpT, const float* __restrict__ hprevT,
    float* __restrict__ houtT, float* __restrict__ cstate,
    const float* __restrict__ Wih, const float* __restrict__ Whh,
    const float* __restrict__ bih, const float* __restrict__ bhh,
    int t, int is_layer0)
{
    float4* wlds = (float4*)myl;              // 8 rows x 128 f4 = 16KB
    float*  red  = myl + 4096;                // [wsub][gate][lane] = 4KB
    const int lane = tsub & 63;

    const float4* Wih4 = (const float4*)Wih;
    const float4* Whh4 = (const float4*)Whh;
    #pragma unroll
    for (int i = 0; i < 4; ++i) {
        int g   = i * 256 + tsub;
        int s   = g >> 7;
        int off = g & 127;
        const float4* src = (s < 4) ? Wih4 : Whh4;
        wlds[g] = src[(size_t)((s & 3) * Hq + h) * 128 + off];
    }
    __syncthreads();

    const int part = wsub >> 1;
    const int kq0  = (wsub & 1) << 6;

    float acc0 = 0.f, acc1 = 0.f, acc2 = 0.f, acc3 = 0.f;

    if (part == 0 && is_layer0) {
        int row = (t == 0) ? xcol[lane * Tq] : (int)(~(unsigned)amax_in[lane]);
        const float4* a4 = (const float4*)(emb + (size_t)row * Eq);
        #pragma unroll 4
        for (int i = 0; i < 64; ++i) {
            float4 a = a4[kq0 + i];
            int kq = kq0 + i;
            float4 w0 = wlds[0 * 128 + kq];
            float4 w1 = wlds[1 * 128 + kq];
            float4 w2 = wlds[2 * 128 + kq];
            float4 w3 = wlds[3 * 128 + kq];
            DOT4(acc0, a, w0); DOT4(acc1, a, w1);
            DOT4(acc2, a, w2); DOT4(acc3, a, w3);
        }
    } else {
        const float4* a4 = (const float4*)(part ? hprevT : inpT);
        #pragma unroll 4
        for (int i = 0; i < 64; ++i) {
            int kq = kq0 + i;
            float4 a = a4[kq * 64 + lane];
            float4 w0 = wlds[(part * 4 + 0) * 128 + kq];
            float4 w1 = wlds[(part * 4 + 1) * 128 + kq];
            float4 w2 = wlds[(part * 4 + 2) * 128 + kq];
            float4 w3 = wlds[(part * 4 + 3) * 128 + kq];
            DOT4(acc0, a, w0); DOT4(acc1, a, w1);
            DOT4(acc2, a, w2); DOT4(acc3, a, w3);
        }
    }

    red[(wsub * 4 + 0) * 64 + lane] = acc0;
    red[(wsub * 4 + 1) * 64 + lane] = acc1;
    red[(wsub * 4 + 2) * 64 + lane] = acc2;
    red[(wsub * 4 + 3) * 64 + lane] = acc3;
    __syncthreads();

    if (wsub == 0) {
        float gi = red[(0*4+0)*64+lane] + red[(1*4+0)*64+lane] + red[(2*4+0)*64+lane] + red[(3*4+0)*64+lane]
                 + bih[0 * Hq + h] + bhh[0 * Hq + h];
        float gf = red[(0*4+1)*64+lane] + red[(1*4+1)*64+lane] + red[(2*4+1)*64+lane] + red[(3*4+1)*64+lane]
                 + bih[1 * Hq + h] + bhh[1 * Hq + h];
        float gg = red[(0*4+2)*64+lane] + red[(1*4+2)*64+lane] + red[(2*4+2)*64+lane] + red[(3*4+2)*64+lane]
                 + bih[2 * Hq + h] + bhh[2 * Hq + h];
        float go = red[(0*4+3)*64+lane] + red[(1*4+3)*64+lane] + red[(2*4+3)*64+lane] + red[(3*4+3)*64+lane]
                 + bih[3 * Hq + h] + bhh[3 * Hq + h];
        float cold = cstate[h * 64 + lane];
        float cn = sigmoid_f(gf) * cold + sigmoid_f(gi) * tanhf(gg);
        float hn = sigmoid_f(go) * tanhf(cn);
        cstate[h * 64 + lane] = cn;
        houtT[(h >> 2) * 256 + lane * 4 + (h & 3)] = hn;
    }
}

// ---------------------------------------------------------------------------
// FC phase: one 64-row vocab tile, 8 waves, K=512 split 8-way (64 floats per
// wave), chunks of 64 double-buffered via global_load_lds, 8x8 register tile,
// 3-level tree reduction, fused bias+argmax epilogue.
// lds = 16384 floats: buf0[0..8191], buf1[8192..16383]; redm reuses 8192+.
// ---------------------------------------------------------------------------
__device__ __forceinline__ void fc_phase(
    float* lds, int v0, int tid, int wave, int lane,
    const float* __restrict__ hT, const float* __restrict__ Wfc,
    const float* __restrict__ bfc, float* __restrict__ out,
    u64* __restrict__ amax, int write_out)
{
    const int rgrp = lane >> 3;
    const int bgrp = lane & 7;

    float acc[8][8];
    #pragma unroll
    for (int j = 0; j < 8; ++j)
        #pragma unroll
        for (int i = 0; i < 8; ++i) acc[j][i] = 0.f;

#define STAGE_CHUNK(cc, dst)                                                  \
    {                                                                         \
        const int k0_ = (cc) * 64;                                            \
        _Pragma("unroll")                                                     \
        for (int it = 0; it < 2; ++it) {                                      \
            int gf = it * 512 + tid;                                          \
            int r = gf >> 4, sp = gf & 15;                                    \
            int gk = k0_ + (((sp ^ (r >> 3)) & 15) << 2);                     \
            gl_lds16(Wfc + (size_t)(v0 + r) * 512 + gk,                       \
                     (dst) + it * 2048 + wave * 256);                         \
        }                                                                     \
        _Pragma("unroll")                                                     \
        for (int it = 0; it < 2; ++it) {                                      \
            int gf = it * 512 + tid;                                          \
            int kqr = gf >> 6, u = gf & 63;                                   \
            int b = (u & 56) | ((u & 7) ^ (u >> 3));                          \
            gl_lds16(hT + (size_t)((cc) * 16 + kqr) * 256 + b * 4,            \
                     (dst) + 4096 + it * 2048 + wave * 256);                  \
        }                                                                     \
    }

    float* cur = lds;
    float* nxt = lds + 8192;

    STAGE_CHUNK(0, cur)
    __syncthreads();

    for (int c = 0; c < 8; ++c) {
        if (c < 7) STAGE_CHUNK(c + 1, nxt)

        #pragma unroll
        for (int kq = 0; kq < 2; ++kq) {
            const int sl = wave * 2 + kq;       // k-slot 0..15 within chunk
            float4 wv[8], av[8];
            #pragma unroll
            for (int j = 0; j < 8; ++j)
                wv[j] = *(const float4*)(cur + (rgrp * 8 + j) * 64 + (((sl ^ rgrp) & 15) << 2));
            #pragma unroll
            for (int i = 0; i < 8; ++i)
                av[i] = *(const float4*)(cur + 4096 + sl * 256 + ((bgrp * 8 + (i ^ bgrp)) << 2));
            #pragma unroll
            for (int j = 0; j < 8; ++j)
                #pragma unroll
                for (int i = 0; i < 8; ++i)
                    DOT4(acc[j][i], av[i], wv[j]);
        }

        __syncthreads();
        float* tmp = cur; cur = nxt; nxt = tmp;
    }
#undef STAGE_CHUNK

#define DUMP_ACC(buf)                                                         \
    _Pragma("unroll")                                                         \
    for (int j = 0; j < 8; ++j) {                                             \
        float* p = (buf) + (rgrp * 8 + j) * 64 + bgrp * 8;                    \
        *(float4*)p       = make_float4(acc[j][0], acc[j][1], acc[j][2], acc[j][3]); \
        *(float4*)(p + 4) = make_float4(acc[j][4], acc[j][5], acc[j][6], acc[j][7]); \
    }
#define ADD_ACC(buf)                                                          \
    _Pragma("unroll")                                                         \
    for (int j = 0; j < 8; ++j) {                                             \
        const float* p = (buf) + (rgrp * 8 + j) * 64 + bgrp * 8;              \
        float4 a0 = *(const float4*)p;                                        \
        float4 a1 = *(const float4*)(p + 4);                                  \
        acc[j][0] += a0.x; acc[j][1] += a0.y; acc[j][2] += a0.z; acc[j][3] += a0.w; \
        acc[j][4] += a1.x; acc[j][5] += a1.y; acc[j][6] += a1.z; acc[j][7] += a1.w; \
    }

    // tree reduction over 8 waves: 8 -> 4 -> 2 -> 1
    if (wave >= 4) DUMP_ACC(lds + (wave - 4) * 4096)
    __syncthreads();
    if (wave < 4)  ADD_ACC(lds + wave * 4096)
    __syncthreads();
    if (wave == 2 || wave == 3) DUMP_ACC(lds + (wave - 2) * 4096)
    __syncthreads();
    if (wave < 2)  ADD_ACC(lds + wave * 4096)
    __syncthreads();
    if (wave == 1) DUMP_ACC(lds)
    __syncthreads();
    if (wave == 0) { ADD_ACC(lds) }
    __syncthreads();
    if (wave == 0) DUMP_ACC(lds)          // final 64x64 tile at lds[0..4095]
    __syncthreads();
#undef DUMP_ACC
#undef ADD_ACC

    // bias + per-batch argmax (8 rows per wave) + optional logit store
    const int b = lane;
    float best = -__builtin_huge_valf();
    int bi = 0;
    float lg[8];
    #pragma unroll
    for (int n = 0; n < 8; ++n) {
        int r = wave * 8 + n;
        float v = lds[r * 64 + b] + bfc[v0 + r];
        lg[n] = v;
        if (v > best) { best = v; bi = v0 + r; }   // '>' keeps smallest index
    }
    u64 pack = ((u64)f2sortable(best) << 32) | (u64)(~(unsigned)bi);

    u64* redm = (u64*)(lds + 8192);
    redm[wave * 64 + b] = pack;
    __syncthreads();
    if (wave == 0) {
        u64 m = redm[b];
        #pragma unroll
        for (int w = 1; w < 8; ++w) { u64 mw = redm[w * 64 + b]; if (mw > m) m = mw; }
        atomicMax(&amax[b], m);
    }
    if (write_out) {
        #pragma unroll
        for (int n = 0; n < 8; ++n)
            out[(size_t)b * Vq + v0 + wave * 8 + n] = lg[n];
    }
}

// ---------------------------------------------------------------------------
// Persistent kernel, plain launch: 256 blocks x 512 threads, 64KB LDS.
// Co-residency by construction: 1-2 blocks/CU always fit (LDS 64<=160KB,
// VGPR capped at 256 by launch_bounds) and 256 blocks <= 256 CUs.
// ---------------------------------------------------------------------------
__global__ __launch_bounds__(512, 2) void fused_kernel(
    const int* __restrict__ x, const float* __restrict__ emb,
    const float* __restrict__ Wih, const float* __restrict__ Whh,
    const float* __restrict__ bih, const float* __restrict__ bhh,
    const float* __restrict__ Wfc, const float* __restrict__ bfc,
    float* __restrict__ out, float* __restrict__ ws)
{
    __shared__ float lds[16384];            // 64KB
    const int tid  = threadIdx.x;
    const int wave = __builtin_amdgcn_readfirstlane(tid >> 6);
    const int lane = tid & 63;
    const int blk  = blockIdx.x;

    float* h0T[2] = { ws,          ws + 32768 };
    float* h1T[2] = { ws + 65536,  ws + 98304 };
    float* c0 = ws + 131072;
    float* c1 = ws + 163840;
    u64* amax = (u64*)(ws + 196608);        // 64 u64 = 128 floats
    unsigned* cnt = (unsigned*)(ws + 196800);
    unsigned* gen = (unsigned*)(ws + 196832);
    // all of the above zeroed by the hipMemsetAsync in kernel_launch

    const int grpu = wave >> 2;             // unit group 0/1
    const int wsub = wave & 3;
    const int tsub = tid & 255;
    const int h    = blk + grpu * 256;      // this group's hidden unit
    float* myl = lds + grpu * 5120;         // 20KB per unit group

    const size_t WL = (size_t)4 * Hq * 512; // per-layer weight stride

    for (int t = 0; t < Tq; ++t) {
        const int rd = t & 1, wr = rd ^ 1;

        // P1: layer 0 (reads amax from previous step's FC)
        lstm_phase(myl, h, wsub, tsub, emb, x, amax,
                   nullptr, h0T[rd], h0T[wr], c0,
                   Wih, Whh, bih, bhh, t, 1);
        gbar(cnt, gen);

        // P2: layer 1; fold in amax reset (consumed in P1, next written in P3)
        if (blk == 0 && tid < 64) amax[tid] = 0;
        lstm_phase(myl, h, wsub, tsub, emb, x, amax,
                   h0T[wr], h1T[rd], h1T[wr], c1,
                   Wih + WL, Whh + WL, bih + 4 * Hq, bhh + 4 * Hq, t, 0);
        gbar(cnt, gen);

        // P3: FC head + argmax; blocks take tile blk and (blk+256 if <500)
        const int wo = (t == Tq - 1) ? 1 : 0;
        fc_phase(lds, blk * 64, tid, wave, lane, h1T[wr], Wfc, bfc, out, amax, wo);
        if (blk + 256 < 500)
            fc_phase(lds, (blk + 256) * 64, tid, wave, lane, h1T[wr], Wfc, bfc, out, amax, wo);
        gbar(cnt, gen);
    }
}

extern "C" void kernel_launch(void* const* d_in, const int* in_sizes, int n_in,
                              void* d_out, int out_size, void* d_ws, size_t ws_size,
                              hipStream_t stream)
{
    const int*   x   = (const int*)d_in[0];
    const float* emb = (const float*)d_in[1];
    const float* Wih = (const float*)d_in[2];
    const float* Whh = (const float*)d_in[3];
    const float* bih = (const float*)d_in[4];
    const float* bhh = (const float*)d_in[5];
    const float* Wfc = (const float*)d_in[6];
    const float* bfc = (const float*)d_in[7];
    float* outp = (float*)d_out;
    float* wsf  = (float*)d_ws;

    // zero h/c state + amax + barrier words (196864 words incl. padding)
    hipMemsetAsync(d_ws, 0, 196864 * sizeof(float), stream);

    fused_kernel<<<NBLK, 512, 0, stream>>>(x, emb, Wih, Whh, bih, bhh,
                                           Wfc, bfc, outp, wsf);
}